// Round 2
// baseline (314.588 us; speedup 1.0000x reference)
//
#include <hip/hip_runtime.h>
#include <hip/hip_bf16.h>

// B=8, N=2048, Q=256, D=1024, H=16, HD=64 cross-attention.
// R8: K/V projection ported to the 8-phase 256x256 template (512 thr, 8 waves
// 2Mx4N, wave-tile 128x64, BK=64, 128 KiB LDS, per-phase half-tile staging,
// vmcnt(4) counted once per K-tile, T2 swizzle, T5 setprio, XCD-chunked block
// swizzle; 512 blocks = exactly 2 rounds). Q projection split into a separate
// small 128^2 kernel (known-good 2-phase core). Scores/PV/out unchanged.

typedef unsigned short u16;
typedef __attribute__((ext_vector_type(8))) short short8;   // 8 bf16 = 4 VGPR
typedef __attribute__((ext_vector_type(4))) float floatx4;  // MFMA acc

static_assert(sizeof(short8) == 16, "short8 must be 16B");

__device__ __forceinline__ u16 f2bf(float f) {
  unsigned int x = __float_as_uint(f);
  x += 0x7fffu + ((x >> 16) & 1u);   // RNE
  return (u16)(x >> 16);
}

// async global->LDS, 16 B per lane; lds = wave-uniform base, lane i -> base+i*16
__device__ __forceinline__ void gload16(const u16* g, u16* lds) {
  __builtin_amdgcn_global_load_lds(
      (const __attribute__((address_space(1))) unsigned int*)g,
      (__attribute__((address_space(3))) unsigned int*)lds, 16, 0, 0);
}

template <int N> __device__ __forceinline__ void vmwait() {
  if constexpr (N == 0)      asm volatile("s_waitcnt vmcnt(0)" ::: "memory");
  else if constexpr (N == 4) asm volatile("s_waitcnt vmcnt(4)" ::: "memory");
  else if constexpr (N == 6) asm volatile("s_waitcnt vmcnt(6)" ::: "memory");
  else if constexpr (N == 8) asm volatile("s_waitcnt vmcnt(8)" ::: "memory");
  else static_assert(N == 0, "unsupported vmcnt immediate");
}

__device__ __forceinline__ void lgkm0() {
  asm volatile("s_waitcnt lgkmcnt(0)" ::: "memory");
}

__device__ __forceinline__ void sfence() { __builtin_amdgcn_sched_barrier(0); }

// ---------------- single fused fp32 -> bf16 cast over all 4 inputs ----------------
__global__ __launch_bounds__(256) void f2bf_multi(
    const float* __restrict__ s, u16* __restrict__ so,
    const float* __restrict__ q, u16* __restrict__ qo,
    const float* __restrict__ wi, u16* __restrict__ wio,
    const float* __restrict__ wo, u16* __restrict__ woo) {
  int i = blockIdx.x * 256 + threadIdx.x;
  const float* in; u16* out; int idx;
  if (i < 4194304)      { in = s;  out = so;  idx = i; }
  else if (i < 4718592) { in = q;  out = qo;  idx = i - 4194304; }
  else if (i < 5505024) { in = wi; out = wio; idx = i - 4718592; }
  else if (i < 5767168) { in = wo; out = woo; idx = i - 5505024; }
  else return;
  float4 v = reinterpret_cast<const float4*>(in)[idx];
  ushort4 o;
  o.x = f2bf(v.x); o.y = f2bf(v.y); o.z = f2bf(v.z); o.w = f2bf(v.w);
  reinterpret_cast<ushort4*>(out)[idx] = o;
}

// ---------------- 2-phase pipelined GEMM core (R7): tile (MT*32)x(NT*32), BK=64 ----
template <int MT, int NT>
__device__ __forceinline__ void gemm_core(
    const u16* __restrict__ A, int lda,
    const u16* __restrict__ Bm, int ldb, int K,
    u16* __restrict__ Alds, u16* __restrict__ Blds,
    floatx4 (&acc)[MT][NT]) {
  const int t = threadIdx.x;
  const int wave = t >> 6, lane = t & 63;
  const int rr = lane & 15, kq = lane >> 4;
  constexpr int AI = MT, BI = NT;
  constexpr int AELEMS = MT * 32 * 64;
  constexpr int BELEMS = NT * 32 * 64;

  const u16* ag[AI]; u16* al[AI];
#pragma unroll
  for (int i = 0; i < AI; ++i) {
    int s = i * 256 + t;
    int row = s >> 3, c16 = s & 7;
    ag[i] = A + (size_t)row * lda + ((c16 ^ (row & 7)) * 8);
    al[i] = Alds + (size_t)(i * 256 + wave * 64) * 8;
  }
  const u16* bg[BI]; u16* blp[BI];
#pragma unroll
  for (int i = 0; i < BI; ++i) {
    int s = i * 256 + t;
    int row = s >> 3, c16 = s & 7;
    bg[i] = Bm + (size_t)row * ldb + ((c16 ^ (row & 7)) * 8);
    blp[i] = Blds + (size_t)(i * 256 + wave * 64) * 8;
  }

  const int m0w = (wave & 1) * (MT * 16);
  const int n0w = (wave >> 1) * (NT * 16);
  int aoff[MT][2], boff[NT][2];
#pragma unroll
  for (int mi = 0; mi < MT; ++mi) {
    int row = m0w + mi * 16 + rr;
#pragma unroll
    for (int kk = 0; kk < 2; ++kk)
      aoff[mi][kk] = row * 64 + (((kk * 4 + kq) ^ (row & 7)) * 8);
  }
#pragma unroll
  for (int ni = 0; ni < NT; ++ni) {
    int row = n0w + ni * 16 + rr;
#pragma unroll
    for (int kk = 0; kk < 2; ++kk)
      boff[ni][kk] = row * 64 + (((kk * 4 + kq) ^ (row & 7)) * 8);
  }

  auto compute = [&](int bs) {
    const u16* Ab = Alds + bs * AELEMS;
    const u16* Bb = Blds + bs * BELEMS;
#pragma unroll
    for (int kk = 0; kk < 2; ++kk) {
      short8 af[MT], bfr[NT];
#pragma unroll
      for (int mi = 0; mi < MT; ++mi)
        af[mi] = *reinterpret_cast<const short8*>(Ab + aoff[mi][kk]);
#pragma unroll
      for (int ni = 0; ni < NT; ++ni)
        bfr[ni] = *reinterpret_cast<const short8*>(Bb + boff[ni][kk]);
      __builtin_amdgcn_s_setprio(1);
#pragma unroll
      for (int mi = 0; mi < MT; ++mi)
#pragma unroll
        for (int ni = 0; ni < NT; ++ni)
          acc[mi][ni] = __builtin_amdgcn_mfma_f32_16x16x32_bf16(af[mi], bfr[ni], acc[mi][ni], 0, 0, 0);
      __builtin_amdgcn_s_setprio(0);
    }
  };

  const int nt = K >> 6;

#pragma unroll
  for (int i = 0; i < AI; ++i) gload16(ag[i], al[i]);
#pragma unroll
  for (int i = 0; i < BI; ++i) gload16(bg[i], blp[i]);

  int cur = 0;
#pragma unroll 1
  for (int tt = 0; tt < nt - 1; ++tt) {
    const int nxt = cur ^ 1;
    const int koff = (tt + 1) * 64;
#pragma unroll
    for (int i = 0; i < AI; ++i) gload16(ag[i] + koff, al[i] + nxt * AELEMS);
#pragma unroll
    for (int i = 0; i < BI; ++i) gload16(bg[i] + koff, blp[i] + nxt * BELEMS);
    sfence();
    vmwait<AI + BI>();
    __builtin_amdgcn_s_barrier();
    sfence();
    compute(cur);
    sfence();
    __builtin_amdgcn_s_barrier();
    cur = nxt;
  }
  sfence();
  vmwait<0>();
  __builtin_amdgcn_s_barrier();
  sfence();
  compute(cur);
}

// ================= 8-phase 256x256 K/V projection =================
// 512 thr, 8 waves (wr=w>>2 in [0,2), wc=w&3 in [0,4)), wave-tile 128x64.
// Per K-tile (BK=64): 4 phases = 4 C-quadrants x 16 MFMA. All frags for the
// K-tile are in regs by end of ph2 -> buffer free; stage 1 half-tile/phase,
// 2 K-tiles ahead; vmcnt(4) once per K-tile (2 half-tiles stay in flight).

template <int LO>
__device__ __forceinline__ void read_a8(const u16* ab, int kcol0, int kcol1,
                                        short8 (&af)[8][2]) {
#pragma unroll
  for (int mi = 0; mi < 4; ++mi) {
    af[LO + mi][0] = *reinterpret_cast<const short8*>(ab + (LO + mi) * 1024 + kcol0);
    af[LO + mi][1] = *reinterpret_cast<const short8*>(ab + (LO + mi) * 1024 + kcol1);
  }
}

template <int LO>
__device__ __forceinline__ void read_b8(const u16* bb, int kcol0, int kcol1,
                                        short8 (&bf)[4][2]) {
#pragma unroll
  for (int ni = 0; ni < 2; ++ni) {
    bf[LO + ni][0] = *reinterpret_cast<const short8*>(bb + (LO + ni) * 1024 + kcol0);
    bf[LO + ni][1] = *reinterpret_cast<const short8*>(bb + (LO + ni) * 1024 + kcol1);
  }
}

template <int M0, int N0>
__device__ __forceinline__ void quad8(const short8 (&af)[8][2], const short8 (&bf)[4][2],
                                      floatx4 (&acc)[8][4]) {
  __builtin_amdgcn_s_setprio(1);
#pragma unroll
  for (int kk = 0; kk < 2; ++kk)
#pragma unroll
    for (int mi = 0; mi < 4; ++mi)
#pragma unroll
      for (int ni = 0; ni < 2; ++ni)
        acc[M0 + mi][N0 + ni] = __builtin_amdgcn_mfma_f32_16x16x32_bf16(
            af[M0 + mi][kk], bf[N0 + ni][kk], acc[M0 + mi][N0 + ni], 0, 0, 0);
  __builtin_amdgcn_s_setprio(0);
}

__global__ __launch_bounds__(512, 2) void gemm_proj_kv8(
    const u16* __restrict__ s_bf, const u16* __restrict__ wi_bf,
    const float* __restrict__ b_in,
    u16* __restrict__ kp, u16* __restrict__ vT) {
  __shared__ __attribute__((aligned(16))) u16 Alds[2 * 256 * 64];  // 64 KiB
  __shared__ __attribute__((aligned(16))) u16 Blds[2 * 256 * 64];  // 64 KiB

  // XCD-chunked bijective swizzle: 512 blocks -> 64 consecutive tiles per XCD
  int bid = blockIdx.y * 8 + blockIdx.x;
  int nb = (bid & 7) * 64 + (bid >> 3);
  const int by = nb >> 3, bx = nb & 7;
  const int mB = by * 256;            // sources row (M = 16384)
  const int nB = bx * 256;            // K/V column (N = 2048)
  const u16* Ag = s_bf + (size_t)mB * 1024;
  const u16* Wg = wi_bf + (size_t)(1024 + nB) * 1024;
  const float* bias = b_in + 1024 + nB;

  const int t = threadIdx.x;
  const int w = t >> 6, lane = t & 63;
  const int rr = lane & 15, kq = lane >> 4;
  const int wr = w >> 2, wc = w & 3;

  // staging sources (inverse-swizzled): LDS linear (row, c16) <- global k-block c16^(row&7)
  const u16* ga[2][2]; const u16* gb[2][2];
#pragma unroll
  for (int h = 0; h < 2; ++h)
#pragma unroll
    for (int i = 0; i < 2; ++i) {
      int s = i * 512 + t;
      int row = h * 128 + (s >> 3), c16 = s & 7;
      ga[h][i] = Ag + (size_t)row * 1024 + ((c16 ^ (row & 7)) * 8);
      gb[h][i] = Wg + (size_t)row * 1024 + ((c16 ^ (row & 7)) * 8);
    }

#define STAGE_A8(j, h) { const int d_ = ((j) & 1) * 16384;                         \
    gload16(ga[h][0] + (size_t)(j) * 64, Alds + d_ + (h) * 8192 + w * 512);        \
    gload16(ga[h][1] + (size_t)(j) * 64, Alds + d_ + (h) * 8192 + 4096 + w * 512); }
#define STAGE_B8(j, h) { const int d_ = ((j) & 1) * 16384;                         \
    gload16(gb[h][0] + (size_t)(j) * 64, Blds + d_ + (h) * 8192 + w * 512);        \
    gload16(gb[h][1] + (size_t)(j) * 64, Blds + d_ + (h) * 8192 + 4096 + w * 512); }

  // fragment read bases: row&7 == rr&7 for all frags -> 2 k-cols cover everything
  const int kcol0 = ((kq) ^ (rr & 7)) * 8;
  const int kcol1 = ((4 + kq) ^ (rr & 7)) * 8;
  const u16* abase = Alds + (wr * 128 + rr) * 64;
  const u16* bbase = Blds + (wc * 64 + rr) * 64;

  short8 af[8][2], bf[4][2];
  const floatx4 zz = {0.f, 0.f, 0.f, 0.f};
  floatx4 acc[8][4];
#pragma unroll
  for (int mi = 0; mi < 8; ++mi)
#pragma unroll
    for (int ni = 0; ni < 4; ++ni) acc[mi][ni] = zz;

  // prologue: kt0 fully + kt1 A0,B0; wait kt0 landed (4 loads stay in flight)
  STAGE_A8(0, 0); STAGE_B8(0, 0); STAGE_A8(0, 1); STAGE_B8(0, 1);
  STAGE_A8(1, 0); STAGE_B8(1, 0);
  sfence();
  vmwait<4>();
  __builtin_amdgcn_s_barrier();
  sfence();

#pragma unroll 1
  for (int kt = 0; kt < 16; ++kt) {
    const int doff = (kt & 1) * 16384;
    const u16* ab = abase + doff;
    const u16* bb = bbase + doff;
    // ---- ph1: read A lo + B lo (12 ds_read); stage A1(kt+1); MFMA q(0,0)
    read_a8<0>(ab, kcol0, kcol1, af);
    read_b8<0>(bb, kcol0, kcol1, bf);
    if (kt + 1 < 16) STAGE_A8(kt + 1, 1);
    sfence();
    __builtin_amdgcn_s_barrier();
    lgkm0(); sfence();
    quad8<0, 0>(af, bf, acc);
    sfence();
    __builtin_amdgcn_s_barrier();
    sfence();
    // ---- ph2: read A hi + B hi; stage B1(kt+1); MFMA q(0,1)
    read_a8<4>(ab, kcol0, kcol1, af);
    read_b8<2>(bb, kcol0, kcol1, bf);
    if (kt + 1 < 16) STAGE_B8(kt + 1, 1);
    sfence();
    __builtin_amdgcn_s_barrier();
    lgkm0(); sfence();
    quad8<0, 2>(af, bf, acc);
    sfence();
    __builtin_amdgcn_s_barrier();
    sfence();
    // ---- ph3: pure MFMA; stage A0(kt+2) into freed buffer; MFMA q(1,0)
    if (kt + 2 < 16) STAGE_A8(kt + 2, 0);
    sfence();
    __builtin_amdgcn_s_barrier();
    quad8<4, 0>(af, bf, acc);
    sfence();
    __builtin_amdgcn_s_barrier();
    sfence();
    // ---- ph4: stage B0(kt+2); counted vmcnt(4) -> kt+1 halves landed,
    //           kt+2's A0/B0 stay in flight; MFMA q(1,1)
    if (kt + 2 < 16) { STAGE_B8(kt + 2, 0); sfence(); vmwait<4>(); }
    else             { sfence(); vmwait<0>(); }
    __builtin_amdgcn_s_barrier();
    quad8<4, 2>(af, bf, acc);
    sfence();
    __builtin_amdgcn_s_barrier();
    sfence();
  }
#undef STAGE_A8
#undef STAGE_B8

  // ---- epilogue: K columns (bx<4) plain store; V columns packed-transposed
  const int r4 = kq * 4;
  const int m0w = wr * 128, n0w = wc * 64;
  if (nB < 1024) {
#pragma unroll
    for (int mi = 0; mi < 8; ++mi)
#pragma unroll
      for (int ni = 0; ni < 4; ++ni) {
        int nl = n0w + ni * 16 + rr;
        float bv = bias[nl];
#pragma unroll
        for (int r = 0; r < 4; ++r) {
          int m = mB + m0w + mi * 16 + r4 + r;
          kp[(size_t)m * 1024 + nB + nl] = f2bf(acc[mi][ni][r] + bv);
        }
      }
  } else {
#pragma unroll
    for (int mi = 0; mi < 8; ++mi)
#pragma unroll
      for (int ni = 0; ni < 4; ++ni) {
        int n2 = nB + n0w + ni * 16 + rr - 1024;
        int h = n2 >> 6, d = n2 & 63;
        float bv = bias[n0w + ni * 16 + rr];
        int m0 = mB + m0w + mi * 16 + r4;   // 4 consecutive rows, same b
        int b = m0 >> 11, j0 = m0 & 2047;
        ushort4 o;
        o.x = f2bf(acc[mi][ni][0] + bv);
        o.y = f2bf(acc[mi][ni][1] + bv);
        o.z = f2bf(acc[mi][ni][2] + bv);
        o.w = f2bf(acc[mi][ni][3] + bv);
        *reinterpret_cast<ushort4*>(
            vT + ((size_t)(b * 16 + h) * 64 + d) * 2048 + j0) = o;
      }
  }
}

// ---- Q projection: small (3% of proj FLOPs), known-good 128^2 2-phase core ----
__global__ __launch_bounds__(256, 2) void gemm_proj_q(
    const u16* __restrict__ qy_bf, const u16* __restrict__ wi_bf,
    const float* __restrict__ b_in, u16* __restrict__ qp) {
  __shared__ __attribute__((aligned(16))) u16 Alds[2 * 128 * 64];
  __shared__ __attribute__((aligned(16))) u16 Blds[2 * 128 * 64];
  const int mB = blockIdx.y * 128;
  const int nB = blockIdx.x * 128;
  const u16* A = qy_bf + (size_t)mB * 1024;
  const u16* W = wi_bf + (size_t)nB * 1024;
  const float* bias = b_in + nB;

  const floatx4 zz = {0.f, 0.f, 0.f, 0.f};
  floatx4 acc[4][4] = {{zz, zz, zz, zz}, {zz, zz, zz, zz}, {zz, zz, zz, zz}, {zz, zz, zz, zz}};
  gemm_core<4, 4>(A, 1024, W, 1024, 1024, Alds, Blds, acc);

  const int lane = threadIdx.x & 63, wave = threadIdx.x >> 6;
  const int rr = lane & 15, r4 = (lane >> 4) * 4;
  const int m0w = (wave & 1) * 64, n0w = (wave >> 1) * 64;
#pragma unroll
  for (int mi = 0; mi < 4; ++mi)
#pragma unroll
    for (int ni = 0; ni < 4; ++ni) {
      int nl = n0w + ni * 16 + rr;
      float bv = bias[nl];
#pragma unroll
      for (int r = 0; r < 4; ++r) {
        int m = mB + m0w + mi * 16 + r4 + r;
        qp[(size_t)m * 1024 + nB + nl] = f2bf((acc[mi][ni][r] + bv) * 0.125f);
      }
    }
}

// ---- scores+exp: P[bz][q][key] = exp(q_h . k_h) (Q pre-scaled by 1/8) ----
__global__ __launch_bounds__(256, 2) void gemm_scores_exp(
    const u16* __restrict__ qp, const u16* __restrict__ kp,
    u16* __restrict__ sc, int b0) {
  __shared__ __attribute__((aligned(16))) u16 Alds[128 * 64];
  __shared__ __attribute__((aligned(16))) u16 Blds[128 * 64];
  const int bz = blockIdx.z, bl = bz >> 4, h = bz & 15;
  const int b = b0 + bl;
  const int mB = blockIdx.y * 128;
  const int nB = blockIdx.x * 128;
  const u16* A = qp + (size_t)b * 256 * 1024 + h * 64 + (size_t)mB * 1024;
  const u16* Bm = kp + (size_t)b * 2048 * 1024 + h * 64 + (size_t)nB * 1024;
  u16* C = sc + (size_t)bz * 256 * 2048;
  const floatx4 zz = {0.f, 0.f, 0.f, 0.f};
  floatx4 acc[4][4] = {{zz, zz, zz, zz}, {zz, zz, zz, zz}, {zz, zz, zz, zz}, {zz, zz, zz, zz}};
  gemm_core<4, 4>(A, 1024, Bm, 1024, 64, Alds, Blds, acc);

  const int lane = threadIdx.x & 63, wave = threadIdx.x >> 6;
  const int rr = lane & 15, r4 = (lane >> 4) * 4;
  const int m0w = (wave & 1) * 64, n0w = (wave >> 1) * 64;
#pragma unroll
  for (int mi = 0; mi < 4; ++mi)
#pragma unroll
    for (int ni = 0; ni < 4; ++ni) {
      int n = nB + n0w + ni * 16 + rr;
#pragma unroll
      for (int r = 0; r < 4; ++r) {
        int m = mB + m0w + mi * 16 + r4 + r;
        C[(size_t)m * 2048 + n] = f2bf(__expf(acc[mi][ni][r]));
      }
    }
}

// ---- PV + l: O = P @ V, l = P @ ones (same GEMM), normalize in epilogue ----
__global__ __launch_bounds__(256, 2) void gemm_pv(
    const u16* __restrict__ sc, const u16* __restrict__ vT,
    u16* __restrict__ ao, int b0) {
  __shared__ __attribute__((aligned(16))) u16 Alds[2 * 64 * 64];
  __shared__ __attribute__((aligned(16))) u16 Blds[2 * 64 * 64];
  const int t = threadIdx.x;
  const int wave = t >> 6, lane = t & 63;
  const int rr = lane & 15, kq = lane >> 4;
  const int bz = blockIdx.z, bl = bz >> 4, h = bz & 15;
  const int b = b0 + bl;
  const int mB = blockIdx.y * 64;
  const u16* A = sc + (size_t)bz * 256 * 2048 + (size_t)mB * 2048;
  const u16* Bm = vT + (size_t)(b * 16 + h) * 64 * 2048;

  const u16* ag[2]; u16* al[2]; const u16* bg[2]; u16* blp[2];
#pragma unroll
  for (int i = 0; i < 2; ++i) {
    int s = i * 256 + t, row = s >> 3, c16 = s & 7;
    ag[i] = A + (size_t)row * 2048 + ((c16 ^ (row & 7)) * 8);
    al[i] = Alds + (size_t)(i * 256 + wave * 64) * 8;
    bg[i] = Bm + (size_t)row * 2048 + ((c16 ^ (row & 7)) * 8);
    blp[i] = Blds + (size_t)(i * 256 + wave * 64) * 8;
  }

  const int m0w = (wave & 1) * 32;
  const int n0w = (wave >> 1) * 32;
  int aoff[2][2], boff[2][2];
#pragma unroll
  for (int mi = 0; mi < 2; ++mi) {
    int row = m0w + mi * 16 + rr;
#pragma unroll
    for (int kk = 0; kk < 2; ++kk)
      aoff[mi][kk] = row * 64 + (((kk * 4 + kq) ^ (row & 7)) * 8);
  }
#pragma unroll
  for (int ni = 0; ni < 2; ++ni) {
    int row = n0w + ni * 16 + rr;
#pragma unroll
    for (int kk = 0; kk < 2; ++kk)
      boff[ni][kk] = row * 64 + (((kk * 4 + kq) ^ (row & 7)) * 8);
  }

  const short ov = (rr == 0) ? (short)0x3F80 : (short)0;
  const short8 ones = {ov, ov, ov, ov, ov, ov, ov, ov};

  const floatx4 zz = {0.f, 0.f, 0.f, 0.f};
  floatx4 acc[2][2] = {{zz, zz}, {zz, zz}};
  floatx4 acc_l[2] = {zz, zz};

  auto compute = [&](int bs) {
    const u16* Ab = Alds + bs * 4096;
    const u16* Bb = Blds + bs * 4096;
#pragma unroll
    for (int kk = 0; kk < 2; ++kk) {
      short8 af[2], bfr[2];
#pragma unroll
      for (int mi = 0; mi < 2; ++mi)
        af[mi] = *reinterpret_cast<const short8*>(Ab + aoff[mi][kk]);
#pragma unroll
      for (int ni = 0; ni < 2; ++ni)
        bfr[ni] = *reinterpret_cast<const short8*>(Bb + boff[ni][kk]);
      __builtin_amdgcn_s_setprio(1);
#pragma unroll
      for (int mi = 0; mi < 2; ++mi) {
#pragma unroll
        for (int ni = 0; ni < 2; ++ni)
          acc[mi][ni] = __builtin_amdgcn_mfma_f32_16x16x32_bf16(af[mi], bfr[ni], acc[mi][ni], 0, 0, 0);
        acc_l[mi] = __builtin_amdgcn_mfma_f32_16x16x32_bf16(af[mi], ones, acc_l[mi], 0, 0, 0);
      }
      __builtin_amdgcn_s_setprio(0);
    }
  };

#pragma unroll
  for (int i = 0; i < 2; ++i) gload16(ag[i], al[i]);
#pragma unroll
  for (int i = 0; i < 2; ++i) gload16(bg[i], blp[i]);

  int cur = 0;
#pragma unroll 1
  for (int tt = 0; tt < 31; ++tt) {
    const int nxt = cur ^ 1;
    const int koff = (tt + 1) * 64;
#pragma unroll
    for (int i = 0; i < 2; ++i) gload16(ag[i] + koff, al[i] + nxt * 4096);
#pragma unroll
    for (int i = 0; i < 2; ++i) gload16(bg[i] + koff, blp[i] + nxt * 4096);
    sfence();
    vmwait<4>();
    __builtin_amdgcn_s_barrier();
    sfence();
    compute(cur);
    sfence();
    __builtin_amdgcn_s_barrier();
    cur = nxt;
  }
  sfence();
  vmwait<0>();
  __builtin_amdgcn_s_barrier();
  sfence();
  compute(cur);

#pragma unroll
  for (int mi = 0; mi < 2; ++mi)
#pragma unroll
    for (int r = 0; r < 4; ++r) {
      float l = __shfl(acc_l[mi][r], lane & 48, 64);
      float inv = 1.0f / l;
      int m = mB + m0w + mi * 16 + kq * 4 + r;
#pragma unroll
      for (int ni = 0; ni < 2; ++ni) {
        int n = n0w + ni * 16 + rr;
        ao[(size_t)(b * 256 + m) * 1024 + h * 64 + n] = f2bf(acc[mi][ni][r] * inv);
      }
    }
}

// ---- out-proj: out = ao @ w_out^T + b_out + queries (fp32), 64x128 tiles ----
__global__ __launch_bounds__(256, 2) void gemm_out(
    const u16* __restrict__ A, const u16* __restrict__ W,
    const float* __restrict__ bias, const float* __restrict__ resid,
    float* __restrict__ out) {
  __shared__ __attribute__((aligned(16))) u16 Alds[2 * 64 * 64];
  __shared__ __attribute__((aligned(16))) u16 Blds[2 * 128 * 64];
  const int mB = blockIdx.y * 64;
  const int nB = blockIdx.x * 128;
  const floatx4 zz = {0.f, 0.f, 0.f, 0.f};
  floatx4 acc[2][4] = {{zz, zz, zz, zz}, {zz, zz, zz, zz}};
  gemm_core<2, 4>(A + (size_t)mB * 1024, 1024, W + (size_t)nB * 1024, 1024, 1024,
                  Alds, Blds, acc);
  const int lane = threadIdx.x & 63, wave = threadIdx.x >> 6;
  const int rr = lane & 15, r4 = (lane >> 4) * 4;
  const int m0w = (wave & 1) * 32, n0w = (wave >> 1) * 64;
#pragma unroll
  for (int mi = 0; mi < 2; ++mi)
#pragma unroll
    for (int ni = 0; ni < 4; ++ni) {
      int n = nB + n0w + ni * 16 + rr;
      float bv = bias[n];
#pragma unroll
      for (int r = 0; r < 4; ++r) {
        int m = mB + m0w + mi * 16 + r4 + r;
        size_t idx = (size_t)m * 1024 + n;
        out[idx] = acc[mi][ni][r] + bv + resid[idx];
      }
    }
}

extern "C" void kernel_launch(void* const* d_in, const int* in_sizes, int n_in,
                              void* d_out, int out_size, void* d_ws, size_t ws_size,
                              hipStream_t stream) {
  const float* sources = (const float*)d_in[0];  // [8,2048,1024]
  const float* queries = (const float*)d_in[1];  // [8,256,1024]
  const float* w_in    = (const float*)d_in[2];  // [3072,1024]
  const float* b_in    = (const float*)d_in[3];  // [3072]
  const float* w_out   = (const float*)d_in[4];  // [1024,1024]
  const float* b_out   = (const float*)d_in[5];  // [1024]
  float* out = (float*)d_out;                    // [8,256,1024] fp32

  char* ws = (char*)d_ws;
  size_t off = 0;
  auto alloc = [&](size_t elems) -> u16* {
    u16* p = (u16*)(ws + off);
    off += elems * sizeof(u16);
    off = (off + 255) & ~(size_t)255;
    return p;
  };
  u16* s_bf  = alloc((size_t)16777216);  // sources bf16
  u16* qy_bf = alloc((size_t)2097152);   // queries bf16
  u16* wi_bf = alloc((size_t)3145728);   // w_in bf16
  u16* wo_bf = alloc((size_t)1048576);   // w_out bf16
  u16* qp    = alloc((size_t)2097152);   // projected q (pre-scaled 1/8)
  u16* kp    = alloc((size_t)16777216);  // projected k
  u16* vT    = alloc((size_t)16777216);  // projected v, [bh][d][n]
  u16* ao    = alloc((size_t)2097152);   // attention output
  const size_t sc_elems_per_b = (size_t)16 * 256 * 2048;
  size_t remain = ws_size > off ? ws_size - off : 0;
  int bchunk = (int)(remain / (sc_elems_per_b * sizeof(u16)));
  if (bchunk > 8) bchunk = 8;
  if (bchunk < 1) bchunk = 1;
  u16* sc = (u16*)(ws + off);

  // 1) casts (single kernel)
  f2bf_multi<<<dim3(22528), 256, 0, stream>>>(
      sources, s_bf, queries, qy_bf, w_in, wi_bf, w_out, wo_bf);

  // 2) projections: K/V on the 8-phase 256^2 template; Q on the small core
  gemm_proj_kv8<<<dim3(8, 64), 512, 0, stream>>>(s_bf, wi_bf, b_in, kp, vT);
  gemm_proj_q<<<dim3(8, 16), 256, 0, stream>>>(qy_bf, wi_bf, b_in, qp);

  // 3) attention: P = exp(QK^T) materialized, then O = P V (+l) -- chunked
  for (int b0 = 0; b0 < 8; b0 += bchunk) {
    int nb = (8 - b0) < bchunk ? (8 - b0) : bchunk;
    gemm_scores_exp<<<dim3(16, 2, nb * 16), 256, 0, stream>>>(qp, kp, sc, b0);
    gemm_pv<<<dim3(1, 4, nb * 16), 256, 0, stream>>>(sc, vT, ao, b0);
  }

  // 4) out-proj + bias + residual
  gemm_out<<<dim3(8, 32), 256, 0, stream>>>(ao, wo_bf, b_out, queries, out);
}

// Round 3
// 275.758 us; speedup vs baseline: 1.1408x; 1.1408x over previous
//
#include <hip/hip_runtime.h>
#include <hip/hip_bf16.h>

// B=8, N=2048, Q=256, D=1024, H=16, HD=64 cross-attention.
// R9: scores+exp+PV fused into one flash-style kernel (no-max softmax makes it
// a plain GEMM->exp->GEMM chain): per (b,h,qhalf) block, Q-tile 128x64 in regs,
// 16 KV-tiles of 128 keys, dbuf K/V staging with counted vmcnt(4), P-tile
// exp'd to XOR-swizzled LDS bf16, O += P.V from reg-accumulated fragments,
// row-sums l in registers (butterfly + LDS combine at end). Eliminates the
// 134 MB sc buffer (write+read) and the chunked launch loop entirely.
// Proj (kv8 + q), casts, out-proj unchanged from R8.

typedef unsigned short u16;
typedef __attribute__((ext_vector_type(8))) short short8;   // 8 bf16 = 4 VGPR
typedef __attribute__((ext_vector_type(4))) float floatx4;  // MFMA acc

static_assert(sizeof(short8) == 16, "short8 must be 16B");

__device__ __forceinline__ u16 f2bf(float f) {
  unsigned int x = __float_as_uint(f);
  x += 0x7fffu + ((x >> 16) & 1u);   // RNE
  return (u16)(x >> 16);
}

__device__ __forceinline__ float bf2f(u16 b) {
  return __uint_as_float(((unsigned int)b) << 16);
}

// async global->LDS, 16 B per lane; lds = wave-uniform base, lane i -> base+i*16
__device__ __forceinline__ void gload16(const u16* g, u16* lds) {
  __builtin_amdgcn_global_load_lds(
      (const __attribute__((address_space(1))) unsigned int*)g,
      (__attribute__((address_space(3))) unsigned int*)lds, 16, 0, 0);
}

template <int N> __device__ __forceinline__ void vmwait() {
  if constexpr (N == 0)      asm volatile("s_waitcnt vmcnt(0)" ::: "memory");
  else if constexpr (N == 4) asm volatile("s_waitcnt vmcnt(4)" ::: "memory");
  else if constexpr (N == 6) asm volatile("s_waitcnt vmcnt(6)" ::: "memory");
  else if constexpr (N == 8) asm volatile("s_waitcnt vmcnt(8)" ::: "memory");
  else static_assert(N == 0, "unsupported vmcnt immediate");
}

__device__ __forceinline__ void lgkm0() {
  asm volatile("s_waitcnt lgkmcnt(0)" ::: "memory");
}

__device__ __forceinline__ void sfence() { __builtin_amdgcn_sched_barrier(0); }

// ---------------- single fused fp32 -> bf16 cast over all 4 inputs ----------------
__global__ __launch_bounds__(256) void f2bf_multi(
    const float* __restrict__ s, u16* __restrict__ so,
    const float* __restrict__ q, u16* __restrict__ qo,
    const float* __restrict__ wi, u16* __restrict__ wio,
    const float* __restrict__ wo, u16* __restrict__ woo) {
  int i = blockIdx.x * 256 + threadIdx.x;
  const float* in; u16* out; int idx;
  if (i < 4194304)      { in = s;  out = so;  idx = i; }
  else if (i < 4718592) { in = q;  out = qo;  idx = i - 4194304; }
  else if (i < 5505024) { in = wi; out = wio; idx = i - 4718592; }
  else if (i < 5767168) { in = wo; out = woo; idx = i - 5505024; }
  else return;
  float4 v = reinterpret_cast<const float4*>(in)[idx];
  ushort4 o;
  o.x = f2bf(v.x); o.y = f2bf(v.y); o.z = f2bf(v.z); o.w = f2bf(v.w);
  reinterpret_cast<ushort4*>(out)[idx] = o;
}

// ---------------- 2-phase pipelined GEMM core: tile (MT*32)x(NT*32), BK=64 ----
template <int MT, int NT>
__device__ __forceinline__ void gemm_core(
    const u16* __restrict__ A, int lda,
    const u16* __restrict__ Bm, int ldb, int K,
    u16* __restrict__ Alds, u16* __restrict__ Blds,
    floatx4 (&acc)[MT][NT]) {
  const int t = threadIdx.x;
  const int wave = t >> 6, lane = t & 63;
  const int rr = lane & 15, kq = lane >> 4;
  constexpr int AI = MT, BI = NT;
  constexpr int AELEMS = MT * 32 * 64;
  constexpr int BELEMS = NT * 32 * 64;

  const u16* ag[AI]; u16* al[AI];
#pragma unroll
  for (int i = 0; i < AI; ++i) {
    int s = i * 256 + t;
    int row = s >> 3, c16 = s & 7;
    ag[i] = A + (size_t)row * lda + ((c16 ^ (row & 7)) * 8);
    al[i] = Alds + (size_t)(i * 256 + wave * 64) * 8;
  }
  const u16* bg[BI]; u16* blp[BI];
#pragma unroll
  for (int i = 0; i < BI; ++i) {
    int s = i * 256 + t;
    int row = s >> 3, c16 = s & 7;
    bg[i] = Bm + (size_t)row * ldb + ((c16 ^ (row & 7)) * 8);
    blp[i] = Blds + (size_t)(i * 256 + wave * 64) * 8;
  }

  const int m0w = (wave & 1) * (MT * 16);
  const int n0w = (wave >> 1) * (NT * 16);
  int aoff[MT][2], boff[NT][2];
#pragma unroll
  for (int mi = 0; mi < MT; ++mi) {
    int row = m0w + mi * 16 + rr;
#pragma unroll
    for (int kk = 0; kk < 2; ++kk)
      aoff[mi][kk] = row * 64 + (((kk * 4 + kq) ^ (row & 7)) * 8);
  }
#pragma unroll
  for (int ni = 0; ni < NT; ++ni) {
    int row = n0w + ni * 16 + rr;
#pragma unroll
    for (int kk = 0; kk < 2; ++kk)
      boff[ni][kk] = row * 64 + (((kk * 4 + kq) ^ (row & 7)) * 8);
  }

  auto compute = [&](int bs) {
    const u16* Ab = Alds + bs * AELEMS;
    const u16* Bb = Blds + bs * BELEMS;
#pragma unroll
    for (int kk = 0; kk < 2; ++kk) {
      short8 af[MT], bfr[NT];
#pragma unroll
      for (int mi = 0; mi < MT; ++mi)
        af[mi] = *reinterpret_cast<const short8*>(Ab + aoff[mi][kk]);
#pragma unroll
      for (int ni = 0; ni < NT; ++ni)
        bfr[ni] = *reinterpret_cast<const short8*>(Bb + boff[ni][kk]);
      __builtin_amdgcn_s_setprio(1);
#pragma unroll
      for (int mi = 0; mi < MT; ++mi)
#pragma unroll
        for (int ni = 0; ni < NT; ++ni)
          acc[mi][ni] = __builtin_amdgcn_mfma_f32_16x16x32_bf16(af[mi], bfr[ni], acc[mi][ni], 0, 0, 0);
      __builtin_amdgcn_s_setprio(0);
    }
  };

  const int nt = K >> 6;

#pragma unroll
  for (int i = 0; i < AI; ++i) gload16(ag[i], al[i]);
#pragma unroll
  for (int i = 0; i < BI; ++i) gload16(bg[i], blp[i]);

  int cur = 0;
#pragma unroll 1
  for (int tt = 0; tt < nt - 1; ++tt) {
    const int nxt = cur ^ 1;
    const int koff = (tt + 1) * 64;
#pragma unroll
    for (int i = 0; i < AI; ++i) gload16(ag[i] + koff, al[i] + nxt * AELEMS);
#pragma unroll
    for (int i = 0; i < BI; ++i) gload16(bg[i] + koff, blp[i] + nxt * BELEMS);
    sfence();
    vmwait<AI + BI>();
    __builtin_amdgcn_s_barrier();
    sfence();
    compute(cur);
    sfence();
    __builtin_amdgcn_s_barrier();
    cur = nxt;
  }
  sfence();
  vmwait<0>();
  __builtin_amdgcn_s_barrier();
  sfence();
  compute(cur);
}

// ================= 8-phase 256x256 K/V projection (R8) =================
template <int LO>
__device__ __forceinline__ void read_a8(const u16* ab, int kcol0, int kcol1,
                                        short8 (&af)[8][2]) {
#pragma unroll
  for (int mi = 0; mi < 4; ++mi) {
    af[LO + mi][0] = *reinterpret_cast<const short8*>(ab + (LO + mi) * 1024 + kcol0);
    af[LO + mi][1] = *reinterpret_cast<const short8*>(ab + (LO + mi) * 1024 + kcol1);
  }
}

template <int LO>
__device__ __forceinline__ void read_b8(const u16* bb, int kcol0, int kcol1,
                                        short8 (&bf)[4][2]) {
#pragma unroll
  for (int ni = 0; ni < 2; ++ni) {
    bf[LO + ni][0] = *reinterpret_cast<const short8*>(bb + (LO + ni) * 1024 + kcol0);
    bf[LO + ni][1] = *reinterpret_cast<const short8*>(bb + (LO + ni) * 1024 + kcol1);
  }
}

template <int M0, int N0>
__device__ __forceinline__ void quad8(const short8 (&af)[8][2], const short8 (&bf)[4][2],
                                      floatx4 (&acc)[8][4]) {
  __builtin_amdgcn_s_setprio(1);
#pragma unroll
  for (int kk = 0; kk < 2; ++kk)
#pragma unroll
    for (int mi = 0; mi < 4; ++mi)
#pragma unroll
      for (int ni = 0; ni < 2; ++ni)
        acc[M0 + mi][N0 + ni] = __builtin_amdgcn_mfma_f32_16x16x32_bf16(
            af[M0 + mi][kk], bf[N0 + ni][kk], acc[M0 + mi][N0 + ni], 0, 0, 0);
  __builtin_amdgcn_s_setprio(0);
}

__global__ __launch_bounds__(512, 2) void gemm_proj_kv8(
    const u16* __restrict__ s_bf, const u16* __restrict__ wi_bf,
    const float* __restrict__ b_in,
    u16* __restrict__ kp, u16* __restrict__ vT) {
  __shared__ __attribute__((aligned(16))) u16 Alds[2 * 256 * 64];  // 64 KiB
  __shared__ __attribute__((aligned(16))) u16 Blds[2 * 256 * 64];  // 64 KiB

  int bid = blockIdx.y * 8 + blockIdx.x;
  int nb = (bid & 7) * 64 + (bid >> 3);
  const int by = nb >> 3, bx = nb & 7;
  const int mB = by * 256;
  const int nB = bx * 256;
  const u16* Ag = s_bf + (size_t)mB * 1024;
  const u16* Wg = wi_bf + (size_t)(1024 + nB) * 1024;
  const float* bias = b_in + 1024 + nB;

  const int t = threadIdx.x;
  const int w = t >> 6, lane = t & 63;
  const int rr = lane & 15, kq = lane >> 4;
  const int wr = w >> 2, wc = w & 3;

  const u16* ga[2][2]; const u16* gb[2][2];
#pragma unroll
  for (int h = 0; h < 2; ++h)
#pragma unroll
    for (int i = 0; i < 2; ++i) {
      int s = i * 512 + t;
      int row = h * 128 + (s >> 3), c16 = s & 7;
      ga[h][i] = Ag + (size_t)row * 1024 + ((c16 ^ (row & 7)) * 8);
      gb[h][i] = Wg + (size_t)row * 1024 + ((c16 ^ (row & 7)) * 8);
    }

#define STAGE_A8(j, h) { const int d_ = ((j) & 1) * 16384;                         \
    gload16(ga[h][0] + (size_t)(j) * 64, Alds + d_ + (h) * 8192 + w * 512);        \
    gload16(ga[h][1] + (size_t)(j) * 64, Alds + d_ + (h) * 8192 + 4096 + w * 512); }
#define STAGE_B8(j, h) { const int d_ = ((j) & 1) * 16384;                         \
    gload16(gb[h][0] + (size_t)(j) * 64, Blds + d_ + (h) * 8192 + w * 512);        \
    gload16(gb[h][1] + (size_t)(j) * 64, Blds + d_ + (h) * 8192 + 4096 + w * 512); }

  const int kcol0 = ((kq) ^ (rr & 7)) * 8;
  const int kcol1 = ((4 + kq) ^ (rr & 7)) * 8;
  const u16* abase = Alds + (wr * 128 + rr) * 64;
  const u16* bbase = Blds + (wc * 64 + rr) * 64;

  short8 af[8][2], bf[4][2];
  const floatx4 zz = {0.f, 0.f, 0.f, 0.f};
  floatx4 acc[8][4];
#pragma unroll
  for (int mi = 0; mi < 8; ++mi)
#pragma unroll
    for (int ni = 0; ni < 4; ++ni) acc[mi][ni] = zz;

  STAGE_A8(0, 0); STAGE_B8(0, 0); STAGE_A8(0, 1); STAGE_B8(0, 1);
  STAGE_A8(1, 0); STAGE_B8(1, 0);
  sfence();
  vmwait<4>();
  __builtin_amdgcn_s_barrier();
  sfence();

#pragma unroll 1
  for (int kt = 0; kt < 16; ++kt) {
    const int doff = (kt & 1) * 16384;
    const u16* ab = abase + doff;
    const u16* bb = bbase + doff;
    read_a8<0>(ab, kcol0, kcol1, af);
    read_b8<0>(bb, kcol0, kcol1, bf);
    if (kt + 1 < 16) STAGE_A8(kt + 1, 1);
    sfence();
    __builtin_amdgcn_s_barrier();
    lgkm0(); sfence();
    quad8<0, 0>(af, bf, acc);
    sfence();
    __builtin_amdgcn_s_barrier();
    sfence();
    read_a8<4>(ab, kcol0, kcol1, af);
    read_b8<2>(bb, kcol0, kcol1, bf);
    if (kt + 1 < 16) STAGE_B8(kt + 1, 1);
    sfence();
    __builtin_amdgcn_s_barrier();
    lgkm0(); sfence();
    quad8<0, 2>(af, bf, acc);
    sfence();
    __builtin_amdgcn_s_barrier();
    sfence();
    if (kt + 2 < 16) STAGE_A8(kt + 2, 0);
    sfence();
    __builtin_amdgcn_s_barrier();
    quad8<4, 0>(af, bf, acc);
    sfence();
    __builtin_amdgcn_s_barrier();
    sfence();
    if (kt + 2 < 16) { STAGE_B8(kt + 2, 0); sfence(); vmwait<4>(); }
    else             { sfence(); vmwait<0>(); }
    __builtin_amdgcn_s_barrier();
    quad8<4, 2>(af, bf, acc);
    sfence();
    __builtin_amdgcn_s_barrier();
    sfence();
  }
#undef STAGE_A8
#undef STAGE_B8

  const int r4 = kq * 4;
  const int m0w = wr * 128, n0w = wc * 64;
  if (nB < 1024) {
#pragma unroll
    for (int mi = 0; mi < 8; ++mi)
#pragma unroll
      for (int ni = 0; ni < 4; ++ni) {
        int nl = n0w + ni * 16 + rr;
        float bv = bias[nl];
#pragma unroll
        for (int r = 0; r < 4; ++r) {
          int m = mB + m0w + mi * 16 + r4 + r;
          kp[(size_t)m * 1024 + nB + nl] = f2bf(acc[mi][ni][r] + bv);
        }
      }
  } else {
#pragma unroll
    for (int mi = 0; mi < 8; ++mi)
#pragma unroll
      for (int ni = 0; ni < 4; ++ni) {
        int n2 = nB + n0w + ni * 16 + rr - 1024;
        int h = n2 >> 6, d = n2 & 63;
        float bv = bias[n0w + ni * 16 + rr];
        int m0 = mB + m0w + mi * 16 + r4;
        int b = m0 >> 11, j0 = m0 & 2047;
        ushort4 o;
        o.x = f2bf(acc[mi][ni][0] + bv);
        o.y = f2bf(acc[mi][ni][1] + bv);
        o.z = f2bf(acc[mi][ni][2] + bv);
        o.w = f2bf(acc[mi][ni][3] + bv);
        *reinterpret_cast<ushort4*>(
            vT + ((size_t)(b * 16 + h) * 64 + d) * 2048 + j0) = o;
      }
  }
}

// ---- Q projection: small (3% of proj FLOPs), 128^2 2-phase core ----
__global__ __launch_bounds__(256, 2) void gemm_proj_q(
    const u16* __restrict__ qy_bf, const u16* __restrict__ wi_bf,
    const float* __restrict__ b_in, u16* __restrict__ qp) {
  __shared__ __attribute__((aligned(16))) u16 Alds[2 * 128 * 64];
  __shared__ __attribute__((aligned(16))) u16 Blds[2 * 128 * 64];
  const int mB = blockIdx.y * 128;
  const int nB = blockIdx.x * 128;
  const u16* A = qy_bf + (size_t)mB * 1024;
  const u16* W = wi_bf + (size_t)nB * 1024;
  const float* bias = b_in + nB;

  const floatx4 zz = {0.f, 0.f, 0.f, 0.f};
  floatx4 acc[4][4] = {{zz, zz, zz, zz}, {zz, zz, zz, zz}, {zz, zz, zz, zz}, {zz, zz, zz, zz}};
  gemm_core<4, 4>(A, 1024, W, 1024, 1024, Alds, Blds, acc);

  const int lane = threadIdx.x & 63, wave = threadIdx.x >> 6;
  const int rr = lane & 15, r4 = (lane >> 4) * 4;
  const int m0w = (wave & 1) * 64, n0w = (wave >> 1) * 64;
#pragma unroll
  for (int mi = 0; mi < 4; ++mi)
#pragma unroll
    for (int ni = 0; ni < 4; ++ni) {
      int nl = n0w + ni * 16 + rr;
      float bv = bias[nl];
#pragma unroll
      for (int r = 0; r < 4; ++r) {
        int m = mB + m0w + mi * 16 + r4 + r;
        qp[(size_t)m * 1024 + nB + nl] = f2bf((acc[mi][ni][r] + bv) * 0.125f);
      }
    }
}

// ================= fused attention: O = softmax-noMax(QK^T) V =================
// 1 block per (b,h,qhalf) = 256 blocks, 512 thr / 8 waves.
// S layout: waves 2(q)x4(key); PV layout: waves 4(q)x2(d).
__global__ __launch_bounds__(512, 2) void attn_fused(
    const u16* __restrict__ qp, const u16* __restrict__ kp,
    const u16* __restrict__ vT, u16* __restrict__ ao) {
  __shared__ __attribute__((aligned(16))) u16 Qlds[8192];       // 128q x 64d
  __shared__ __attribute__((aligned(16))) u16 Klds[2][8192];    // 128key x 64d
  __shared__ __attribute__((aligned(16))) u16 Vlds[2][8192];    // 64d x 128key
  __shared__ __attribute__((aligned(16))) u16 Plds[16384];      // 128q x 128key
  __shared__ float l_part[4][128];

  // XCD swizzle: qhalf-pairs (same b,h -> same K/V) land on the same XCD
  const int bid = blockIdx.x;
  const int nb = (bid & 7) * 32 + (bid >> 3);
  const int bh = nb >> 1, qh = nb & 1;
  const int b = bh >> 4, h = bh & 15;

  const int t = threadIdx.x;
  const int w = t >> 6, lane = t & 63;
  const int rr = lane & 15, kq = lane >> 4;
  const int swz = rr & 7;
  const int wrS = w >> 2, wcS = w & 3;     // S: q-block 64, key-block 32
  const int wrP = w >> 1, wcP = w & 1;     // PV: q-block 32, d-block 32

  // staging addresses (inverse-swizzled global source, linear LDS dest)
  const u16* qg[2]; const u16* kg[2]; const u16* vg[2];
  {
    const u16* qbase = qp + ((size_t)(b * 256 + qh * 128)) * 1024 + h * 64;
    const u16* kbase = kp + ((size_t)b * 2048) * 1024 + h * 64;
    const u16* vbase = vT + ((size_t)bh * 64) * 2048;
#pragma unroll
    for (int i = 0; i < 2; ++i) {
      int s = i * 512 + t;
      int r8 = s >> 3, c8 = s & 7;          // 128 rows x 8 slots
      int r16 = s >> 4, c16 = s & 15;       // 64 rows x 16 slots
      qg[i] = qbase + (size_t)r8 * 1024 + ((c8 ^ (r8 & 7)) * 8);
      kg[i] = kbase + (size_t)r8 * 1024 + ((c8 ^ (r8 & 7)) * 8);
      vg[i] = vbase + (size_t)r16 * 2048 + ((c16 ^ (r16 & 7)) * 8);
    }
  }

  float l_acc[4][4];
#pragma unroll
  for (int mi = 0; mi < 4; ++mi)
#pragma unroll
    for (int r = 0; r < 4; ++r) l_acc[mi][r] = 0.f;
  const floatx4 zz = {0.f, 0.f, 0.f, 0.f};
  floatx4 oacc[2][2] = {{zz, zz}, {zz, zz}};

  // prologue: Q + KV tile 0
  ((float*)l_part)[t] = 0.f;
#pragma unroll
  for (int i = 0; i < 2; ++i) gload16(qg[i], Qlds + (i * 512 + w * 64) * 8);
#pragma unroll
  for (int i = 0; i < 2; ++i) gload16(kg[i], &Klds[0][(i * 512 + w * 64) * 8]);
#pragma unroll
  for (int i = 0; i < 2; ++i) gload16(vg[i], &Vlds[0][(i * 512 + w * 64) * 8]);
  sfence();
  vmwait<0>();
  __builtin_amdgcn_s_barrier();
  sfence();

  // Q fragments (held in regs for the whole kernel)
  short8 qf[4][2];
#pragma unroll
  for (int mi = 0; mi < 4; ++mi) {
    int qrow = wrS * 64 + mi * 16 + rr;
#pragma unroll
    for (int kc = 0; kc < 2; ++kc)
      qf[mi][kc] = *reinterpret_cast<const short8*>(
          Qlds + qrow * 64 + (((kc * 4 + kq) ^ swz) * 8));
  }

#pragma unroll 1
  for (int kt = 0; kt < 16; ++kt) {
    const int buf = kt & 1;
    if (kt) { sfence(); __builtin_amdgcn_s_barrier(); sfence(); }
    if (kt < 15) {
      const int nxt = buf ^ 1;
      const size_t ko = (size_t)(kt + 1) * 131072;   // 128 rows * 1024
      const size_t vo = (size_t)(kt + 1) * 128;      // 128 keys
#pragma unroll
      for (int i = 0; i < 2; ++i) gload16(kg[i] + ko, &Klds[nxt][(i * 512 + w * 64) * 8]);
#pragma unroll
      for (int i = 0; i < 2; ++i) gload16(vg[i] + vo, &Vlds[nxt][(i * 512 + w * 64) * 8]);
      sfence();
      vmwait<4>();
    } else {
      sfence();
      vmwait<0>();
    }
    // ---- S = Q K^T (C: row=q, col=key)
    short8 kf[2][2];
#pragma unroll
    for (int ni = 0; ni < 2; ++ni) {
      int krow = wcS * 32 + ni * 16 + rr;
#pragma unroll
      for (int kc = 0; kc < 2; ++kc)
        kf[ni][kc] = *reinterpret_cast<const short8*>(
            &Klds[buf][krow * 64 + (((kc * 4 + kq) ^ swz) * 8)]);
    }
    lgkm0(); sfence();
    floatx4 sacc[4][2];
#pragma unroll
    for (int mi = 0; mi < 4; ++mi)
#pragma unroll
      for (int ni = 0; ni < 2; ++ni) sacc[mi][ni] = zz;
    __builtin_amdgcn_s_setprio(1);
#pragma unroll
    for (int kc = 0; kc < 2; ++kc)
#pragma unroll
      for (int mi = 0; mi < 4; ++mi)
#pragma unroll
        for (int ni = 0; ni < 2; ++ni)
          sacc[mi][ni] = __builtin_amdgcn_mfma_f32_16x16x32_bf16(
              qf[mi][kc], kf[ni][kc], sacc[mi][ni], 0, 0, 0);
    __builtin_amdgcn_s_setprio(0);
    sfence();
    // ---- P = exp(S) -> swizzled LDS bf16; l partials in regs
#pragma unroll
    for (int mi = 0; mi < 4; ++mi) {
#pragma unroll
      for (int r = 0; r < 4; ++r) {
        int qr = wrS * 64 + mi * 16 + kq * 4 + r;
        int rb = qr * 128;
        int qsw = qr & 7;
        float lsum = 0.f;
#pragma unroll
        for (int ni = 0; ni < 2; ++ni) {
          int key = wcS * 32 + ni * 16 + rr;
          u16 pb = f2bf(__expf(sacc[mi][ni][r]));
          Plds[rb + ((((key >> 3) ^ qsw)) << 3) + (key & 7)] = pb;
          lsum += bf2f(pb);
        }
        l_acc[mi][r] += lsum;
      }
    }
    lgkm0();
    sfence();
    __builtin_amdgcn_s_barrier();
    sfence();
    // ---- O += P V (A=P rows q, B=V rows d; k = key)
    short8 pa[2][4], vf[2][4];
#pragma unroll
    for (int mi = 0; mi < 2; ++mi) {
      int qrow = wrP * 32 + mi * 16 + rr;
#pragma unroll
      for (int kc = 0; kc < 4; ++kc)
        pa[mi][kc] = *reinterpret_cast<const short8*>(
            Plds + qrow * 128 + ((((kc * 4 + kq) ^ swz)) << 3));
    }
#pragma unroll
    for (int ni = 0; ni < 2; ++ni) {
      int drow = wcP * 32 + ni * 16 + rr;
#pragma unroll
      for (int kc = 0; kc < 4; ++kc)
        vf[ni][kc] = *reinterpret_cast<const short8*>(
            &Vlds[buf][drow * 128 + ((((kc * 4 + kq) ^ swz)) << 3)]);
    }
    lgkm0(); sfence();
    __builtin_amdgcn_s_setprio(1);
#pragma unroll
    for (int kc = 0; kc < 4; ++kc)
#pragma unroll
      for (int mi = 0; mi < 2; ++mi)
#pragma unroll
        for (int ni = 0; ni < 2; ++ni)
          oacc[mi][ni] = __builtin_amdgcn_mfma_f32_16x16x32_bf16(
              pa[mi][kc], vf[ni][kc], oacc[mi][ni], 0, 0, 0);
    __builtin_amdgcn_s_setprio(0);
    sfence();
  }

  // ---- l reduce: butterfly over the 16-lane rr group, combine across wcS waves
#pragma unroll
  for (int mi = 0; mi < 4; ++mi)
#pragma unroll
    for (int r = 0; r < 4; ++r) {
      float v = l_acc[mi][r];
      v += __shfl_xor(v, 1, 64);
      v += __shfl_xor(v, 2, 64);
      v += __shfl_xor(v, 4, 64);
      v += __shfl_xor(v, 8, 64);
      l_acc[mi][r] = v;
    }
  if (rr == 0) {
#pragma unroll
    for (int mi = 0; mi < 4; ++mi)
#pragma unroll
      for (int r = 0; r < 4; ++r)
        l_part[wcS][wrS * 64 + mi * 16 + kq * 4 + r] = l_acc[mi][r];
  }
  __syncthreads();

  // ---- normalize + store
  u16* aob = ao + ((size_t)(b * 256 + qh * 128)) * 1024 + h * 64;
#pragma unroll
  for (int mi = 0; mi < 2; ++mi)
#pragma unroll
    for (int r = 0; r < 4; ++r) {
      int q = wrP * 32 + mi * 16 + kq * 4 + r;
      float inv = 1.0f / (l_part[0][q] + l_part[1][q] + l_part[2][q] + l_part[3][q]);
#pragma unroll
      for (int ni = 0; ni < 2; ++ni) {
        int d = wcP * 32 + ni * 16 + rr;
        aob[(size_t)q * 1024 + d] = f2bf(oacc[mi][ni][r] * inv);
      }
    }
}

// ---- out-proj: out = ao @ w_out^T + b_out + queries (fp32), 64x128 tiles ----
__global__ __launch_bounds__(256, 2) void gemm_out(
    const u16* __restrict__ A, const u16* __restrict__ W,
    const float* __restrict__ bias, const float* __restrict__ resid,
    float* __restrict__ out) {
  __shared__ __attribute__((aligned(16))) u16 Alds[2 * 64 * 64];
  __shared__ __attribute__((aligned(16))) u16 Blds[2 * 128 * 64];
  const int mB = blockIdx.y * 64;
  const int nB = blockIdx.x * 128;
  const floatx4 zz = {0.f, 0.f, 0.f, 0.f};
  floatx4 acc[2][4] = {{zz, zz, zz, zz}, {zz, zz, zz, zz}};
  gemm_core<2, 4>(A + (size_t)mB * 1024, 1024, W + (size_t)nB * 1024, 1024, 1024,
                  Alds, Blds, acc);
  const int lane = threadIdx.x & 63, wave = threadIdx.x >> 6;
  const int rr = lane & 15, r4 = (lane >> 4) * 4;
  const int m0w = (wave & 1) * 32, n0w = (wave >> 1) * 64;
#pragma unroll
  for (int mi = 0; mi < 2; ++mi)
#pragma unroll
    for (int ni = 0; ni < 4; ++ni) {
      int n = nB + n0w + ni * 16 + rr;
      float bv = bias[n];
#pragma unroll
      for (int r = 0; r < 4; ++r) {
        int m = mB + m0w + mi * 16 + r4 + r;
        size_t idx = (size_t)m * 1024 + n;
        out[idx] = acc[mi][ni][r] + bv + resid[idx];
      }
    }
}

extern "C" void kernel_launch(void* const* d_in, const int* in_sizes, int n_in,
                              void* d_out, int out_size, void* d_ws, size_t ws_size,
                              hipStream_t stream) {
  const float* sources = (const float*)d_in[0];  // [8,2048,1024]
  const float* queries = (const float*)d_in[1];  // [8,256,1024]
  const float* w_in    = (const float*)d_in[2];  // [3072,1024]
  const float* b_in    = (const float*)d_in[3];  // [3072]
  const float* w_out   = (const float*)d_in[4];  // [1024,1024]
  const float* b_out   = (const float*)d_in[5];  // [1024]
  float* out = (float*)d_out;                    // [8,256,1024] fp32

  char* ws = (char*)d_ws;
  size_t off = 0;
  auto alloc = [&](size_t elems) -> u16* {
    u16* p = (u16*)(ws + off);
    off += elems * sizeof(u16);
    off = (off + 255) & ~(size_t)255;
    return p;
  };
  u16* s_bf  = alloc((size_t)16777216);  // sources bf16
  u16* qy_bf = alloc((size_t)2097152);   // queries bf16
  u16* wi_bf = alloc((size_t)3145728);   // w_in bf16
  u16* wo_bf = alloc((size_t)1048576);   // w_out bf16
  u16* qp    = alloc((size_t)2097152);   // projected q (pre-scaled 1/8)
  u16* kp    = alloc((size_t)16777216);  // projected k
  u16* vT    = alloc((size_t)16777216);  // projected v, [bh][d][n]
  u16* ao    = alloc((size_t)2097152);   // attention output

  // 1) casts
  f2bf_multi<<<dim3(22528), 256, 0, stream>>>(
      sources, s_bf, queries, qy_bf, w_in, wi_bf, w_out, wo_bf);

  // 2) projections
  gemm_proj_kv8<<<dim3(8, 64), 512, 0, stream>>>(s_bf, wi_bf, b_in, kp, vT);
  gemm_proj_q<<<dim3(8, 16), 256, 0, stream>>>(qy_bf, wi_bf, b_in, qp);

  // 3) fused attention (no sc buffer, no chunk loop)
  attn_fused<<<dim3(256), 512, 0, stream>>>(qp, kp, vT, ao);

  // 4) out-proj + bias + residual
  gemm_out<<<dim3(8, 32), 256, 0, stream>>>(ao, wo_bf, b_out, queries, out);
}

// Round 5
// 267.600 us; speedup vs baseline: 1.1756x; 1.0305x over previous
//
#include <hip/hip_runtime.h>
#include <hip/hip_bf16.h>

// B=8, N=2048, Q=256, D=1024, H=16, HD=64 cross-attention.
// R11 = R10 resubmission (previous round failed on container infra, no kernel
// signal). attn_fused: swapped QK^T (S^T = K.Q) so each lane holds 4
// consecutive keys of one q -> P stored via v_cvt_pk_bf16_f32 pairs as
// ds_write_b64 (8/thread/tile vs 32 scalar); row-sum l via ones-MFMA in PV
// (no LDS, no shuffle); 64q x 128key tiles, LDS = exactly 80 KiB (Q staged
// into P region) -> 2 blocks/CU; V 1-ahead + K 2-ahead counted-vmcnt pipeline,
// per-wave vmwait BEFORE each barrier. Proj (kv8+q), casts, out unchanged.

typedef unsigned short u16;
typedef __attribute__((ext_vector_type(8))) short short8;   // 8 bf16 = 4 VGPR
typedef __attribute__((ext_vector_type(4))) float floatx4;  // MFMA acc

static_assert(sizeof(short8) == 16, "short8 must be 16B");

__device__ __forceinline__ u16 f2bf(float f) {
  unsigned int x = __float_as_uint(f);
  x += 0x7fffu + ((x >> 16) & 1u);   // RNE
  return (u16)(x >> 16);
}

// pack 2 f32 -> 2 bf16 (RNE) in one instruction
__device__ __forceinline__ unsigned int cvtpk(float lo, float hi) {
  unsigned int r;
  asm("v_cvt_pk_bf16_f32 %0, %1, %2" : "=v"(r) : "v"(lo), "v"(hi));
  return r;
}

// async global->LDS, 16 B per lane; lds = wave-uniform base, lane i -> base+i*16
__device__ __forceinline__ void gload16(const u16* g, u16* lds) {
  __builtin_amdgcn_global_load_lds(
      (const __attribute__((address_space(1))) unsigned int*)g,
      (__attribute__((address_space(3))) unsigned int*)lds, 16, 0, 0);
}

template <int N> __device__ __forceinline__ void vmwait() {
  if constexpr (N == 0)      asm volatile("s_waitcnt vmcnt(0)" ::: "memory");
  else if constexpr (N == 2) asm volatile("s_waitcnt vmcnt(2)" ::: "memory");
  else if constexpr (N == 4) asm volatile("s_waitcnt vmcnt(4)" ::: "memory");
  else if constexpr (N == 6) asm volatile("s_waitcnt vmcnt(6)" ::: "memory");
  else if constexpr (N == 8) asm volatile("s_waitcnt vmcnt(8)" ::: "memory");
  else static_assert(N == 0, "unsupported vmcnt immediate");
}

__device__ __forceinline__ void lgkm0() {
  asm volatile("s_waitcnt lgkmcnt(0)" ::: "memory");
}

__device__ __forceinline__ void sfence() { __builtin_amdgcn_sched_barrier(0); }

// ---------------- single fused fp32 -> bf16 cast over all 4 inputs ----------------
__global__ __launch_bounds__(256) void f2bf_multi(
    const float* __restrict__ s, u16* __restrict__ so,
    const float* __restrict__ q, u16* __restrict__ qo,
    const float* __restrict__ wi, u16* __restrict__ wio,
    const float* __restrict__ wo, u16* __restrict__ woo) {
  int i = blockIdx.x * 256 + threadIdx.x;
  const float* in; u16* out; int idx;
  if (i < 4194304)      { in = s;  out = so;  idx = i; }
  else if (i < 4718592) { in = q;  out = qo;  idx = i - 4194304; }
  else if (i < 5505024) { in = wi; out = wio; idx = i - 4718592; }
  else if (i < 5767168) { in = wo; out = woo; idx = i - 5505024; }
  else return;
  float4 v = reinterpret_cast<const float4*>(in)[idx];
  ushort4 o;
  o.x = f2bf(v.x); o.y = f2bf(v.y); o.z = f2bf(v.z); o.w = f2bf(v.w);
  reinterpret_cast<ushort4*>(out)[idx] = o;
}

// ---------------- 2-phase pipelined GEMM core: tile (MT*32)x(NT*32), BK=64 ----
template <int MT, int NT>
__device__ __forceinline__ void gemm_core(
    const u16* __restrict__ A, int lda,
    const u16* __restrict__ Bm, int ldb, int K,
    u16* __restrict__ Alds, u16* __restrict__ Blds,
    floatx4 (&acc)[MT][NT]) {
  const int t = threadIdx.x;
  const int wave = t >> 6, lane = t & 63;
  const int rr = lane & 15, kq = lane >> 4;
  constexpr int AI = MT, BI = NT;
  constexpr int AELEMS = MT * 32 * 64;
  constexpr int BELEMS = NT * 32 * 64;

  const u16* ag[AI]; u16* al[AI];
#pragma unroll
  for (int i = 0; i < AI; ++i) {
    int s = i * 256 + t;
    int row = s >> 3, c16 = s & 7;
    ag[i] = A + (size_t)row * lda + ((c16 ^ (row & 7)) * 8);
    al[i] = Alds + (size_t)(i * 256 + wave * 64) * 8;
  }
  const u16* bg[BI]; u16* blp[BI];
#pragma unroll
  for (int i = 0; i < BI; ++i) {
    int s = i * 256 + t;
    int row = s >> 3, c16 = s & 7;
    bg[i] = Bm + (size_t)row * ldb + ((c16 ^ (row & 7)) * 8);
    blp[i] = Blds + (size_t)(i * 256 + wave * 64) * 8;
  }

  const int m0w = (wave & 1) * (MT * 16);
  const int n0w = (wave >> 1) * (NT * 16);
  int aoff[MT][2], boff[NT][2];
#pragma unroll
  for (int mi = 0; mi < MT; ++mi) {
    int row = m0w + mi * 16 + rr;
#pragma unroll
    for (int kk = 0; kk < 2; ++kk)
      aoff[mi][kk] = row * 64 + (((kk * 4 + kq) ^ (row & 7)) * 8);
  }
#pragma unroll
  for (int ni = 0; ni < NT; ++ni) {
    int row = n0w + ni * 16 + rr;
#pragma unroll
    for (int kk = 0; kk < 2; ++kk)
      boff[ni][kk] = row * 64 + (((kk * 4 + kq) ^ (row & 7)) * 8);
  }

  auto compute = [&](int bs) {
    const u16* Ab = Alds + bs * AELEMS;
    const u16* Bb = Blds + bs * BELEMS;
#pragma unroll
    for (int kk = 0; kk < 2; ++kk) {
      short8 af[MT], bfr[NT];
#pragma unroll
      for (int mi = 0; mi < MT; ++mi)
        af[mi] = *reinterpret_cast<const short8*>(Ab + aoff[mi][kk]);
#pragma unroll
      for (int ni = 0; ni < NT; ++ni)
        bfr[ni] = *reinterpret_cast<const short8*>(Bb + boff[ni][kk]);
      __builtin_amdgcn_s_setprio(1);
#pragma unroll
      for (int mi = 0; mi < MT; ++mi)
#pragma unroll
        for (int ni = 0; ni < NT; ++ni)
          acc[mi][ni] = __builtin_amdgcn_mfma_f32_16x16x32_bf16(af[mi], bfr[ni], acc[mi][ni], 0, 0, 0);
      __builtin_amdgcn_s_setprio(0);
    }
  };

  const int nt = K >> 6;

#pragma unroll
  for (int i = 0; i < AI; ++i) gload16(ag[i], al[i]);
#pragma unroll
  for (int i = 0; i < BI; ++i) gload16(bg[i], blp[i]);

  int cur = 0;
#pragma unroll 1
  for (int tt = 0; tt < nt - 1; ++tt) {
    const int nxt = cur ^ 1;
    const int koff = (tt + 1) * 64;
#pragma unroll
    for (int i = 0; i < AI; ++i) gload16(ag[i] + koff, al[i] + nxt * AELEMS);
#pragma unroll
    for (int i = 0; i < BI; ++i) gload16(bg[i] + koff, blp[i] + nxt * BELEMS);
    sfence();
    vmwait<AI + BI>();
    __builtin_amdgcn_s_barrier();
    sfence();
    compute(cur);
    sfence();
    __builtin_amdgcn_s_barrier();
    cur = nxt;
  }
  sfence();
  vmwait<0>();
  __builtin_amdgcn_s_barrier();
  sfence();
  compute(cur);
}

// ================= 8-phase 256x256 K/V projection (R8) =================
template <int LO>
__device__ __forceinline__ void read_a8(const u16* ab, int kcol0, int kcol1,
                                        short8 (&af)[8][2]) {
#pragma unroll
  for (int mi = 0; mi < 4; ++mi) {
    af[LO + mi][0] = *reinterpret_cast<const short8*>(ab + (LO + mi) * 1024 + kcol0);
    af[LO + mi][1] = *reinterpret_cast<const short8*>(ab + (LO + mi) * 1024 + kcol1);
  }
}

template <int LO>
__device__ __forceinline__ void read_b8(const u16* bb, int kcol0, int kcol1,
                                        short8 (&bf)[4][2]) {
#pragma unroll
  for (int ni = 0; ni < 2; ++ni) {
    bf[LO + ni][0] = *reinterpret_cast<const short8*>(bb + (LO + ni) * 1024 + kcol0);
    bf[LO + ni][1] = *reinterpret_cast<const short8*>(bb + (LO + ni) * 1024 + kcol1);
  }
}

template <int M0, int N0>
__device__ __forceinline__ void quad8(const short8 (&af)[8][2], const short8 (&bf)[4][2],
                                      floatx4 (&acc)[8][4]) {
  __builtin_amdgcn_s_setprio(1);
#pragma unroll
  for (int kk = 0; kk < 2; ++kk)
#pragma unroll
    for (int mi = 0; mi < 4; ++mi)
#pragma unroll
      for (int ni = 0; ni < 2; ++ni)
        acc[M0 + mi][N0 + ni] = __builtin_amdgcn_mfma_f32_16x16x32_bf16(
            af[M0 + mi][kk], bf[N0 + ni][kk], acc[M0 + mi][N0 + ni], 0, 0, 0);
  __builtin_amdgcn_s_setprio(0);
}

__global__ __launch_bounds__(512, 2) void gemm_proj_kv8(
    const u16* __restrict__ s_bf, const u16* __restrict__ wi_bf,
    const float* __restrict__ b_in,
    u16* __restrict__ kp, u16* __restrict__ vT) {
  __shared__ __attribute__((aligned(16))) u16 Alds[2 * 256 * 64];  // 64 KiB
  __shared__ __attribute__((aligned(16))) u16 Blds[2 * 256 * 64];  // 64 KiB

  int bid = blockIdx.y * 8 + blockIdx.x;
  int nb = (bid & 7) * 64 + (bid >> 3);
  const int by = nb >> 3, bx = nb & 7;
  const int mB = by * 256;
  const int nB = bx * 256;
  const u16* Ag = s_bf + (size_t)mB * 1024;
  const u16* Wg = wi_bf + (size_t)(1024 + nB) * 1024;
  const float* bias = b_in + 1024 + nB;

  const int t = threadIdx.x;
  const int w = t >> 6, lane = t & 63;
  const int rr = lane & 15, kq = lane >> 4;
  const int wr = w >> 2, wc = w & 3;

  const u16* ga[2][2]; const u16* gb[2][2];
#pragma unroll
  for (int h = 0; h < 2; ++h)
#pragma unroll
    for (int i = 0; i < 2; ++i) {
      int s = i * 512 + t;
      int row = h * 128 + (s >> 3), c16 = s & 7;
      ga[h][i] = Ag + (size_t)row * 1024 + ((c16 ^ (row & 7)) * 8);
      gb[h][i] = Wg + (size_t)row * 1024 + ((c16 ^ (row & 7)) * 8);
    }

#define STAGE_A8(j, h) { const int d_ = ((j) & 1) * 16384;                         \
    gload16(ga[h][0] + (size_t)(j) * 64, Alds + d_ + (h) * 8192 + w * 512);        \
    gload16(ga[h][1] + (size_t)(j) * 64, Alds + d_ + (h) * 8192 + 4096 + w * 512); }
#define STAGE_B8(j, h) { const int d_ = ((j) & 1) * 16384;                         \
    gload16(gb[h][0] + (size_t)(j) * 64, Blds + d_ + (h) * 8192 + w * 512);        \
    gload16(gb[h][1] + (size_t)(j) * 64, Blds + d_ + (h) * 8192 + 4096 + w * 512); }

  const int kcol0 = ((kq) ^ (rr & 7)) * 8;
  const int kcol1 = ((4 + kq) ^ (rr & 7)) * 8;
  const u16* abase = Alds + (wr * 128 + rr) * 64;
  const u16* bbase = Blds + (wc * 64 + rr) * 64;

  short8 af[8][2], bf[4][2];
  const floatx4 zz = {0.f, 0.f, 0.f, 0.f};
  floatx4 acc[8][4];
#pragma unroll
  for (int mi = 0; mi < 8; ++mi)
#pragma unroll
    for (int ni = 0; ni < 4; ++ni) acc[mi][ni] = zz;

  STAGE_A8(0, 0); STAGE_B8(0, 0); STAGE_A8(0, 1); STAGE_B8(0, 1);
  STAGE_A8(1, 0); STAGE_B8(1, 0);
  sfence();
  vmwait<4>();
  __builtin_amdgcn_s_barrier();
  sfence();

#pragma unroll 1
  for (int kt = 0; kt < 16; ++kt) {
    const int doff = (kt & 1) * 16384;
    const u16* ab = abase + doff;
    const u16* bb = bbase + doff;
    read_a8<0>(ab, kcol0, kcol1, af);
    read_b8<0>(bb, kcol0, kcol1, bf);
    if (kt + 1 < 16) STAGE_A8(kt + 1, 1);
    sfence();
    __builtin_amdgcn_s_barrier();
    lgkm0(); sfence();
    quad8<0, 0>(af, bf, acc);
    sfence();
    __builtin_amdgcn_s_barrier();
    sfence();
    read_a8<4>(ab, kcol0, kcol1, af);
    read_b8<2>(bb, kcol0, kcol1, bf);
    if (kt + 1 < 16) STAGE_B8(kt + 1, 1);
    sfence();
    __builtin_amdgcn_s_barrier();
    lgkm0(); sfence();
    quad8<0, 2>(af, bf, acc);
    sfence();
    __builtin_amdgcn_s_barrier();
    sfence();
    if (kt + 2 < 16) STAGE_A8(kt + 2, 0);
    sfence();
    __builtin_amdgcn_s_barrier();
    quad8<4, 0>(af, bf, acc);
    sfence();
    __builtin_amdgcn_s_barrier();
    sfence();
    if (kt + 2 < 16) { STAGE_B8(kt + 2, 0); sfence(); vmwait<4>(); }
    else             { sfence(); vmwait<0>(); }
    __builtin_amdgcn_s_barrier();
    quad8<4, 2>(af, bf, acc);
    sfence();
    __builtin_amdgcn_s_barrier();
    sfence();
  }
#undef STAGE_A8
#undef STAGE_B8

  const int r4 = kq * 4;
  const int m0w = wr * 128, n0w = wc * 64;
  if (nB < 1024) {
#pragma unroll
    for (int mi = 0; mi < 8; ++mi)
#pragma unroll
      for (int ni = 0; ni < 4; ++ni) {
        int nl = n0w + ni * 16 + rr;
        float bv = bias[nl];
#pragma unroll
        for (int r = 0; r < 4; ++r) {
          int m = mB + m0w + mi * 16 + r4 + r;
          kp[(size_t)m * 1024 + nB + nl] = f2bf(acc[mi][ni][r] + bv);
        }
      }
  } else {
#pragma unroll
    for (int mi = 0; mi < 8; ++mi)
#pragma unroll
      for (int ni = 0; ni < 4; ++ni) {
        int n2 = nB + n0w + ni * 16 + rr - 1024;
        int h = n2 >> 6, d = n2 & 63;
        float bv = bias[n0w + ni * 16 + rr];
        int m0 = mB + m0w + mi * 16 + r4;
        int b = m0 >> 11, j0 = m0 & 2047;
        ushort4 o;
        o.x = f2bf(acc[mi][ni][0] + bv);
        o.y = f2bf(acc[mi][ni][1] + bv);
        o.z = f2bf(acc[mi][ni][2] + bv);
        o.w = f2bf(acc[mi][ni][3] + bv);
        *reinterpret_cast<ushort4*>(
            vT + ((size_t)(b * 16 + h) * 64 + d) * 2048 + j0) = o;
      }
  }
}

// ---- Q projection: small (3% of proj FLOPs), 128^2 2-phase core ----
__global__ __launch_bounds__(256, 2) void gemm_proj_q(
    const u16* __restrict__ qy_bf, const u16* __restrict__ wi_bf,
    const float* __restrict__ b_in, u16* __restrict__ qp) {
  __shared__ __attribute__((aligned(16))) u16 Alds[2 * 128 * 64];
  __shared__ __attribute__((aligned(16))) u16 Blds[2 * 128 * 64];
  const int mB = blockIdx.y * 128;
  const int nB = blockIdx.x * 128;
  const u16* A = qy_bf + (size_t)mB * 1024;
  const u16* W = wi_bf + (size_t)nB * 1024;
  const float* bias = b_in + nB;

  const floatx4 zz = {0.f, 0.f, 0.f, 0.f};
  floatx4 acc[4][4] = {{zz, zz, zz, zz}, {zz, zz, zz, zz}, {zz, zz, zz, zz}, {zz, zz, zz, zz}};
  gemm_core<4, 4>(A, 1024, W, 1024, 1024, Alds, Blds, acc);

  const int lane = threadIdx.x & 63, wave = threadIdx.x >> 6;
  const int rr = lane & 15, r4 = (lane >> 4) * 4;
  const int m0w = (wave & 1) * 64, n0w = (wave >> 1) * 64;
#pragma unroll
  for (int mi = 0; mi < 4; ++mi)
#pragma unroll
    for (int ni = 0; ni < 4; ++ni) {
      int nl = n0w + ni * 16 + rr;
      float bv = bias[nl];
#pragma unroll
      for (int r = 0; r < 4; ++r) {
        int m = mB + m0w + mi * 16 + r4 + r;
        qp[(size_t)m * 1024 + nB + nl] = f2bf((acc[mi][ni][r] + bv) * 0.125f);
      }
    }
}

// ================= fused attention: S^T swap + packed P + ones-l =========
// 1 block per (b,h,qquarter): 512 blocks, 512 thr / 8 waves, 2 blocks/CU.
// S^T: waves 4(key)x2(q), wave tile 32key x 32q. PV: waves 2(q)x4(d),
// wave tile 32q x 16d. LDS: K dbuf 32K + V dbuf 32K + P 16K (Q overlaid) = 80K.
__global__ __launch_bounds__(512, 4) void attn_fused(
    const u16* __restrict__ qp, const u16* __restrict__ kp,
    const u16* __restrict__ vT, u16* __restrict__ ao) {
  __shared__ __attribute__((aligned(16))) u16 Klds[2][8192];  // [128key][64d]
  __shared__ __attribute__((aligned(16))) u16 Vlds[2][8192];  // [64d][128key]
  __shared__ __attribute__((aligned(16))) u16 Plds[8192];     // [64q][128key]; first 4096 = Q stage

  // XCD-chunked swizzle: all 4 q-blocks of a (b,h) on one XCD
  const int bid = blockIdx.x;
  const int nb = (bid & 7) * 64 + (bid >> 3);
  const int bh = nb >> 2, qb = nb & 3;
  const int b = bh >> 4, h = bh & 15;

  const int t = threadIdx.x;
  const int w = t >> 6, lane = t & 63;
  const int rr = lane & 15, kq = lane >> 4;
  const int wk = w >> 1, wq = w & 1;     // S^T wave grid
  const int wPq = w >> 2, wPd = w & 3;   // PV wave grid

  // staging addresses (inverse-swizzled global source, linear LDS dest)
  const u16* qg;
  const u16* kg[2];
  const u16* vg[2];
  {
    const u16* qbase = qp + ((size_t)(b * 256 + qb * 64)) * 1024 + h * 64;
    const u16* kbase = kp + ((size_t)b * 2048) * 1024 + h * 64;
    const u16* vbase = vT + ((size_t)bh * 64) * 2048;
    { int row = t >> 3, c8 = t & 7;
      qg = qbase + (size_t)row * 1024 + ((c8 ^ (row & 7)) * 8); }
#pragma unroll
    for (int i = 0; i < 2; ++i) {
      int s = i * 512 + t;
      int r8 = s >> 3, c8 = s & 7;
      int r16 = s >> 4, c16 = s & 15;
      kg[i] = kbase + (size_t)r8 * 1024 + ((c8 ^ (r8 & 7)) * 8);
      vg[i] = vbase + (size_t)r16 * 2048 + ((c16 ^ (r16 & 7)) * 8);
    }
  }

#define STAGE_K(j) { u16* d_ = &Klds[(j) & 1][w * 512];                 \
    gload16(kg[0] + (size_t)(j) * 131072, d_);                          \
    gload16(kg[1] + (size_t)(j) * 131072, d_ + 4096); }
#define STAGE_V(j) { u16* d_ = &Vlds[(j) & 1][w * 512];                 \
    gload16(vg[0] + (size_t)(j) * 128, d_);                             \
    gload16(vg[1] + (size_t)(j) * 128, d_ + 4096); }

  // prologue: Q -> P region, K0, V0, K1
  gload16(qg, Plds + w * 512);
  STAGE_K(0); STAGE_V(0); STAGE_K(1);
  sfence();
  vmwait<6>();                       // Q landed (K0,V0,K1 fly)
  __builtin_amdgcn_s_barrier();
  sfence();
  short8 qf[2][2];
#pragma unroll
  for (int ni = 0; ni < 2; ++ni) {
    int qrow = wq * 32 + ni * 16 + rr;
#pragma unroll
    for (int kc = 0; kc < 2; ++kc)
      qf[ni][kc] = *reinterpret_cast<const short8*>(
          Plds + qrow * 64 + (((kc * 4 + kq) ^ (qrow & 7)) * 8));
  }
  lgkm0(); sfence();
  vmwait<2>();                       // K0,V0 landed (K1 flies)
  __builtin_amdgcn_s_barrier();      // Q reads done by all -> P writable
  sfence();

  const short ov = (rr == 0) ? (short)0x3F80 : (short)0;
  const short8 ones = {ov, ov, ov, ov, ov, ov, ov, ov};
  const floatx4 zz = {0.f, 0.f, 0.f, 0.f};
  floatx4 oacc[2] = {zz, zz};
  floatx4 acc_l[2] = {zz, zz};

  const int pq0 = wq * 32 + rr;             // + ni*16
  const int pkb = wk * 4 + (kq >> 1);       // + mi*2
  const int pk4 = (kq & 1) * 4;

#pragma unroll 1
  for (int kt = 0; kt < 16; ++kt) {
    const int buf = kt & 1;
    if (kt + 1 < 16) STAGE_V(kt + 1);       // into vbuf((kt+1)&1), freed last iter
    sfence();
    // ---- S^T = K.Q: lane holds 4 consecutive keys of one q
    short8 kf[2][2];
#pragma unroll
    for (int mi = 0; mi < 2; ++mi) {
      int krow = wk * 32 + mi * 16 + rr;
#pragma unroll
      for (int kc = 0; kc < 2; ++kc)
        kf[mi][kc] = *reinterpret_cast<const short8*>(
            &Klds[buf][krow * 64 + (((kc * 4 + kq) ^ (krow & 7)) * 8)]);
    }
    lgkm0(); sfence();
    floatx4 sacc[2][2] = {{zz, zz}, {zz, zz}};
    __builtin_amdgcn_s_setprio(1);
#pragma unroll
    for (int kc = 0; kc < 2; ++kc)
#pragma unroll
      for (int mi = 0; mi < 2; ++mi)
#pragma unroll
        for (int ni = 0; ni < 2; ++ni)
          sacc[mi][ni] = __builtin_amdgcn_mfma_f32_16x16x32_bf16(
              kf[mi][kc], qf[ni][kc], sacc[mi][ni], 0, 0, 0);
    __builtin_amdgcn_s_setprio(0);
    sfence();
    // ---- P = exp(S): cvt_pk pairs, one ds_write_b64 per fragment
#pragma unroll
    for (int mi = 0; mi < 2; ++mi) {
      int kb = pkb + mi * 2;
#pragma unroll
      for (int ni = 0; ni < 2; ++ni) {
        int q = pq0 + ni * 16;
        float e0 = __expf(sacc[mi][ni][0]);
        float e1 = __expf(sacc[mi][ni][1]);
        float e2 = __expf(sacc[mi][ni][2]);
        float e3 = __expf(sacc[mi][ni][3]);
        uint2 pv;
        pv.x = cvtpk(e0, e1);
        pv.y = cvtpk(e2, e3);
        *reinterpret_cast<uint2*>(
            &Plds[q * 128 + ((kb ^ (q & 7)) << 3) + pk4]) = pv;
      }
    }
    lgkm0(); sfence();
    if (kt < 15) vmwait<4>(); else vmwait<0>();   // V(kt) landed per-wave
    __builtin_amdgcn_s_barrier();                 // P visible; V(kt) all-waves
    sfence();
    // ---- O += P.V ; l += P.ones
    short8 pa[2][4], vf[4];
#pragma unroll
    for (int mi = 0; mi < 2; ++mi) {
      int qrow = wPq * 32 + mi * 16 + rr;
#pragma unroll
      for (int kc = 0; kc < 4; ++kc)
        pa[mi][kc] = *reinterpret_cast<const short8*>(
            Plds + qrow * 128 + (((kc * 4 + kq) ^ (qrow & 7)) << 3));
    }
    {
      int drow = wPd * 16 + rr;
#pragma unroll
      for (int kc = 0; kc < 4; ++kc)
        vf[kc] = *reinterpret_cast<const short8*>(
            &Vlds[buf][drow * 128 + (((kc * 4 + kq) ^ (drow & 7)) << 3)]);
    }
    lgkm0(); sfence();
    if (kt + 2 < 16) STAGE_K(kt + 2);       // kbuf(kt&1): K(kt) reads done at barrier
    sfence();
    __builtin_amdgcn_s_setprio(1);
#pragma unroll
    for (int kc = 0; kc < 4; ++kc)
#pragma unroll
      for (int mi = 0; mi < 2; ++mi) {
        oacc[mi] = __builtin_amdgcn_mfma_f32_16x16x32_bf16(
            pa[mi][kc], vf[kc], oacc[mi], 0, 0, 0);
        acc_l[mi] = __builtin_amdgcn_mfma_f32_16x16x32_bf16(
            pa[mi][kc], ones, acc_l[mi], 0, 0, 0);
      }
    __builtin_amdgcn_s_setprio(0);
    sfence();
    if (kt + 1 < 16) {
      if (kt + 2 < 16) vmwait<4>(); else vmwait<2>();  // K(kt+1) landed per-wave
    }
    __builtin_amdgcn_s_barrier();   // PV reads done -> V/K bufs reusable
    sfence();
  }
#undef STAGE_K
#undef STAGE_V

  // ---- normalize + store: l broadcast from col-0 lanes (rr==0, same kq)
  u16* aob = ao + ((size_t)(b * 256 + qb * 64)) * 1024 + h * 64;
#pragma unroll
  for (int mi = 0; mi < 2; ++mi)
#pragma unroll
    for (int r = 0; r < 4; ++r) {
      float l = __shfl(acc_l[mi][r], lane & 48, 64);
      float inv = 1.0f / l;
      int q = wPq * 32 + mi * 16 + kq * 4 + r;
      int d = wPd * 16 + rr;
      aob[(size_t)q * 1024 + d] = f2bf(oacc[mi][r] * inv);
    }
}

// ---- out-proj: out = ao @ w_out^T + b_out + queries (fp32), 64x128 tiles ----
__global__ __launch_bounds__(256, 2) void gemm_out(
    const u16* __restrict__ A, const u16* __restrict__ W,
    const float* __restrict__ bias, const float* __restrict__ resid,
    float* __restrict__ out) {
  __shared__ __attribute__((aligned(16))) u16 Alds[2 * 64 * 64];
  __shared__ __attribute__((aligned(16))) u16 Blds[2 * 128 * 64];
  const int mB = blockIdx.y * 64;
  const int nB = blockIdx.x * 128;
  const floatx4 zz = {0.f, 0.f, 0.f, 0.f};
  floatx4 acc[2][4] = {{zz, zz, zz, zz}, {zz, zz, zz, zz}};
  gemm_core<2, 4>(A + (size_t)mB * 1024, 1024, W + (size_t)nB * 1024, 1024, 1024,
                  Alds, Blds, acc);
  const int lane = threadIdx.x & 63, wave = threadIdx.x >> 6;
  const int rr = lane & 15, r4 = (lane >> 4) * 4;
  const int m0w = (wave & 1) * 32, n0w = (wave >> 1) * 64;
#pragma unroll
  for (int mi = 0; mi < 2; ++mi)
#pragma unroll
    for (int ni = 0; ni < 4; ++ni) {
      int n = nB + n0w + ni * 16 + rr;
      float bv = bias[n];
#pragma unroll
      for (int r = 0; r < 4; ++r) {
        int m = mB + m0w + mi * 16 + r4 + r;
        size_t idx = (size_t)m * 1024 + n;
        out[idx] = acc[mi][ni][r] + bv + resid[idx];
      }
    }
}

extern "C" void kernel_launch(void* const* d_in, const int* in_sizes, int n_in,
                              void* d_out, int out_size, void* d_ws, size_t ws_size,
                              hipStream_t stream) {
  const float* sources = (const float*)d_in[0];  // [8,2048,1024]
  const float* queries = (const float*)d_in[1];  // [8,256,1024]
  const float* w_in    = (const float*)d_in[2];  // [3072,1024]
  const float* b_in    = (const float*)d_in[3];  // [3072]
  const float* w_out   = (const float*)d_in[4];  // [1024,1024]
  const float* b_out   = (const float*)d_in[5];  // [1024]
  float* out = (float*)d_out;                    // [8,256,1024] fp32

  char* ws = (char*)d_ws;
  size_t off = 0;
  auto alloc = [&](size_t elems) -> u16* {
    u16* p = (u16*)(ws + off);
    off += elems * sizeof(u16);
    off = (off + 255) & ~(size_t)255;
    return p;
  };
  u16* s_bf  = alloc((size_t)16777216);  // sources bf16
  u16* qy_bf = alloc((size_t)2097152);   // queries bf16
  u16* wi_bf = alloc((size_t)3145728);   // w_in bf16
  u16* wo_bf = alloc((size_t)1048576);   // w_out bf16
  u16* qp    = alloc((size_t)2097152);   // projected q (pre-scaled 1/8)
  u16* kp    = alloc((size_t)16777216);  // projected k
  u16* vT    = alloc((size_t)16777216);  // projected v, [bh][d][n]
  u16* ao    = alloc((size_t)2097152);   // attention output

  // 1) casts
  f2bf_multi<<<dim3(22528), 256, 0, stream>>>(
      sources, s_bf, queries, qy_bf, w_in, wi_bf, w_out, wo_bf);

  // 2) projections
  gemm_proj_kv8<<<dim3(8, 64), 512, 0, stream>>>(s_bf, wi_bf, b_in, kp, vT);
  gemm_proj_q<<<dim3(8, 16), 256, 0, stream>>>(qy_bf, wi_bf, b_in, qp);

  // 3) fused attention (S^T swap, packed P, ones-l, 2 blocks/CU)
  attn_fused<<<dim3(512), 512, 0, stream>>>(qp, kp, vT, ao);

  // 4) out-proj + bias + residual
  gemm_out<<<dim3(8, 32), 256, 0, stream>>>(ao, wo_bf, b_out, queries, out);
}